// Round 11
// baseline (185.433 us; speedup 1.0000x reference)
//
#include <hip/hip_runtime.h>

// phase modulation, real-part output: out = x_r*cos(2*pi*p) - x_i*sin(2*pi*p)
// inside centered 256x256 window; out = x_r elsewhere.
// R7/R10: both ~2.4 TB/s, VALU 14-19%, occ 47-66% -> latency-bound burst-drain.
// R11: persistent grid (2048 blocks = 8/CU, full residency) + 2-stage software
// pipeline (prefetch next tile's xr while finishing current) to keep loads in
// flight continuously. Window logic / nt stores unchanged from R10.

#define TWO_PI 6.283185307179586f

constexpr int M = 512;
constexpr int N = 256;
constexpr int START = 128;
constexpr int CH = 9;

typedef float floatx4 __attribute__((ext_vector_type(4)));

__device__ __forceinline__ float4 mod4(float4 r, float4 im, float4 p) {
    float s0, c0, s1, c1, s2, c2, s3, c3;
    sincosf(TWO_PI * p.x, &s0, &c0);
    sincosf(TWO_PI * p.y, &s1, &c1);
    sincosf(TWO_PI * p.z, &s2, &c2);
    sincosf(TWO_PI * p.w, &s3, &c3);
    float4 o;
    o.x = r.x * c0 - im.x * s0;
    o.y = r.y * c1 - im.y * s1;
    o.z = r.z * c2 - im.z * s2;
    o.w = r.w * c3 - im.w * s3;
    return o;
}

__device__ __forceinline__ void nt_store4(float* dst, float4 v) {
    floatx4 nv;
    nv.x = v.x; nv.y = v.y; nv.z = v.z; nv.w = v.w;
    __builtin_nontemporal_store(nv, reinterpret_cast<floatx4*>(dst));
}

// Persistent: 2048 blocks x 256 thr; thread handles one float4 per iteration,
// 9 iterations (4,718,592 float4 / 524,288 threads). Prefetch next xr.
constexpr int GRID = 2048;
constexpr int BLOCK = 256;
constexpr long STRIDE4 = (long)GRID * BLOCK;        // float4s per grid-iteration
constexpr int ITERS = 9;                            // 4718592 / 524288

__global__ __launch_bounds__(256) void phase_mod_real_pipe(
    const float* __restrict__ xr,
    const float* __restrict__ xi,
    const float* __restrict__ phase,
    float* __restrict__ out)
{
    const long g0 = (long)blockIdx.x * BLOCK + threadIdx.x;   // float4 index

    float4 r_next = *reinterpret_cast<const float4*>(xr + 4 * g0);

    #pragma unroll
    for (int i = 0; i < ITERS; ++i) {
        const long g = g0 + (long)i * STRIDE4;
        const long e = 4 * g;
        float4 r = r_next;
        if (i + 1 < ITERS) {
            r_next = *reinterpret_cast<const float4*>(xr + e + 4 * STRIDE4);
        }

        const int col     = (int)(e & (M - 1));
        const int rowflat = (int)(e >> 9);
        const int row     = rowflat & (M - 1);
        const bool inside = ((unsigned)(row - START) < (unsigned)N) &&
                            ((unsigned)(col - START) < (unsigned)N);
        if (inside) {
            const int chan = (rowflat >> 9) % CH;
            const long pidx = (long)chan * (N * N) + (long)(row - START) * N + (col - START);
            float4 p  = *reinterpret_cast<const float4*>(phase + pidx);
            float4 im = *reinterpret_cast<const float4*>(xi + e);
            r = mod4(r, im, p);
        }
        nt_store4(out + e, r);
    }
}

// ---- mode B (defensive, if out_size >= 2n): interleaved complex64 ----
__global__ __launch_bounds__(256) void phase_mod_cplx_kernel(
    const float* __restrict__ xr,
    const float* __restrict__ xi,
    const float* __restrict__ phase,
    float* __restrict__ out,
    int nvec4)
{
    int t = blockIdx.x * blockDim.x + threadIdx.x;
    if (t >= nvec4) return;
    long e = (long)t * 4;
    int col     = (int)(e & (M - 1));
    int rowflat = (int)(e >> 9);
    int row     = rowflat & (M - 1);

    float4 r  = *reinterpret_cast<const float4*>(xr + e);
    float4 im = *reinterpret_cast<const float4*>(xi + e);
    float4 o0 = make_float4(r.x, im.x, r.y, im.y);
    float4 o1 = make_float4(r.z, im.z, r.w, im.w);

    bool inside = ((unsigned)(row - START) < (unsigned)N) &&
                  ((unsigned)(col - START) < (unsigned)N);
    if (inside) {
        int chan = (rowflat >> 9) % CH;
        long pidx = (long)chan * (N * N) + (long)(row - START) * N + (col - START);
        float4 p = *reinterpret_cast<const float4*>(phase + pidx);
        float s0, c0, s1, c1, s2, c2, s3, c3;
        sincosf(TWO_PI * p.x, &s0, &c0);
        sincosf(TWO_PI * p.y, &s1, &c1);
        sincosf(TWO_PI * p.z, &s2, &c2);
        sincosf(TWO_PI * p.w, &s3, &c3);
        o0.x = r.x * c0 - im.x * s0;  o0.y = r.x * s0 + im.x * c0;
        o0.z = r.y * c1 - im.y * s1;  o0.w = r.y * s1 + im.y * c1;
        o1.x = r.z * c2 - im.z * s2;  o1.y = r.z * s2 + im.z * c2;
        o1.z = r.w * c3 - im.w * s3;  o1.w = r.w * s3 + im.w * c3;
    }
    *reinterpret_cast<float4*>(out + 2 * e)     = o0;
    *reinterpret_cast<float4*>(out + 2 * e + 4) = o1;
}

extern "C" void kernel_launch(void* const* d_in, const int* in_sizes, int n_in,
                              void* d_out, int out_size, void* d_ws, size_t ws_size,
                              hipStream_t stream) {
    const float* xr    = (const float*)d_in[0];
    const float* xi    = (const float*)d_in[1];
    const float* phase = (const float*)d_in[2];
    float* out = (float*)d_out;

    long n = in_sizes[0];            // 18,874,368
    if ((long)out_size >= 2 * n) {
        int nvec4 = (int)(n / 4);
        int grid = (nvec4 + 255) / 256;
        phase_mod_cplx_kernel<<<grid, 256, 0, stream>>>(xr, xi, phase, out, nvec4);
    } else {
        phase_mod_real_pipe<<<GRID, BLOCK, 0, stream>>>(xr, xi, phase, out);
    }
}